// Round 6
// baseline (5991.624 us; speedup 1.0000x reference)
//
#include <hip/hip_runtime.h>
#include <hip/hip_bf16.h>
#include <stdint.h>

// LSTM: B=32, T=1024, C=512, H=512. out = [T,B,H] fp32 ++ hT[1,B,H] ++ cT[1,B,H].
// Phase 1: x-projection GEMM (bf16 MFMA), bias folded, stored bf16 in ws.
// Phase 2: persistent 64-block recurrent kernel.
//   R6: h_{t-1} loaded straight into registers via a sched_barrier-pinned batch
//       of relaxed-agent 8B loads (no LDS staging -> no 8-way bank conflicts);
//       W_hh in registers; distributed per-block flag barrier (own 64B line per
//       block, one wave-gather + ballot to check all 64) -- no serialized adds.

#define B_N 32
#define T_N 1024
#define C_N 512
#define H_N 512
#define G_N 2048
#define NBLK 64
#define JPB 8   // H / NBLK

typedef __attribute__((ext_vector_type(8))) short bf16x8;
typedef __attribute__((ext_vector_type(4))) short s16x4;
typedef __attribute__((ext_vector_type(4))) float f32x4;

__device__ __forceinline__ short f2bf(float f) {
  union { float f; unsigned u; } x; x.f = f;
  unsigned r = x.u + 0x7fffu + ((x.u >> 16) & 1u);   // RNE
  return (short)(r >> 16);
}
__device__ __forceinline__ float bf2f(short s) {
  union { unsigned u; float f; } x; x.u = ((unsigned)(unsigned short)s) << 16;
  return x.f;
}
__device__ __forceinline__ float sigmoid_f(float x) {
  return 1.f / (1.f + __expf(-x));
}
__device__ __forceinline__ float tanh_f(float x) {
  return 1.f - 2.f / (__expf(2.f * x) + 1.f);
}

// ---------------------------------------------------------------------------
// Pack W_hh (fp32 [2048][512]) -> bf16, per-recurrent-block column order:
// Wpack[bid][n'][k], n' = gate*8 + (j&7), where g = gate*512 + j, bid = j>>3.
__global__ __launch_bounds__(256) void pack_whh(const float* __restrict__ Whh,
                                                short* __restrict__ Wpack) {
  int idx = blockIdx.x * 256 + threadIdx.x;   // 131072 threads
  int g  = idx >> 6;                          // 0..2047
  int kb = (idx & 63) * 8;                    // 0..504
  int gate = g >> 9, j = g & 511;
  int bid = j >> 3, np = gate * 8 + (j & 7);
  const float* sp = Whh + (size_t)g * C_N + kb;
  float4 v0 = *(const float4*)(sp);
  float4 v1 = *(const float4*)(sp + 4);
  bf16x8 o;
  o[0] = f2bf(v0.x); o[1] = f2bf(v0.y); o[2] = f2bf(v0.z); o[3] = f2bf(v0.w);
  o[4] = f2bf(v1.x); o[5] = f2bf(v1.y); o[6] = f2bf(v1.z); o[7] = f2bf(v1.w);
  *(bf16x8*)(Wpack + ((size_t)(bid * 32 + np)) * C_N + kb) = o;
}

// ---------------------------------------------------------------------------
// x-projection GEMM: xp[t][bid][b][n'] (bf16) = src[b][t0+t][:] . W_ih[g][:] + b_ih[g] + b_hh[g]
__global__ __launch_bounds__(256) void xproj_gemm(const float* __restrict__ src,
                                                  const float* __restrict__ Wih,
                                                  const float* __restrict__ bih,
                                                  const float* __restrict__ bhh,
                                                  short* __restrict__ xp, int t0) {
  __shared__ short As[64][72];
  __shared__ short Bs[64][72];
  int tid = threadIdx.x;
  int bn = blockIdx.x & 31, bm = blockIdx.x >> 5;
  int mbase = bm * 64, nbase = bn * 64;
  int lane = tid & 63, wave = tid >> 6;
  int lm = lane & 15, q = lane >> 4;
  int m0 = (wave & 1) * 32, n0 = (wave >> 1) * 32;
  f32x4 acc[2][2] = {};

  for (int kk = 0; kk < C_N; kk += 64) {
    for (int p = 0; p < 4; ++p) {
      int flat = p * 1024 + tid * 4;
      int r = flat >> 6, k = flat & 63;
      int m = mbase + r; int tl = m >> 5, b = m & 31;
      float4 va = *(const float4*)(src + ((size_t)b * T_N + (t0 + tl)) * C_N + kk + k);
      s16x4 pa; pa[0] = f2bf(va.x); pa[1] = f2bf(va.y); pa[2] = f2bf(va.z); pa[3] = f2bf(va.w);
      *(s16x4*)&As[r][k] = pa;
      int gg = nbase + r;
      float4 vb = *(const float4*)(Wih + (size_t)gg * C_N + kk + k);
      s16x4 pb; pb[0] = f2bf(vb.x); pb[1] = f2bf(vb.y); pb[2] = f2bf(vb.z); pb[3] = f2bf(vb.w);
      *(s16x4*)&Bs[r][k] = pb;
    }
    __syncthreads();
    for (int ks = 0; ks < 2; ++ks) {
      bf16x8 a0 = *(bf16x8*)&As[m0 + lm][ks * 32 + q * 8];
      bf16x8 a1 = *(bf16x8*)&As[m0 + 16 + lm][ks * 32 + q * 8];
      bf16x8 b0 = *(bf16x8*)&Bs[n0 + lm][ks * 32 + q * 8];
      bf16x8 b1 = *(bf16x8*)&Bs[n0 + 16 + lm][ks * 32 + q * 8];
      acc[0][0] = __builtin_amdgcn_mfma_f32_16x16x32_bf16(a0, b0, acc[0][0], 0, 0, 0);
      acc[0][1] = __builtin_amdgcn_mfma_f32_16x16x32_bf16(a0, b1, acc[0][1], 0, 0, 0);
      acc[1][0] = __builtin_amdgcn_mfma_f32_16x16x32_bf16(a1, b0, acc[1][0], 0, 0, 0);
      acc[1][1] = __builtin_amdgcn_mfma_f32_16x16x32_bf16(a1, b1, acc[1][1], 0, 0, 0);
    }
    __syncthreads();
  }
  for (int nt = 0; nt < 2; ++nt) {
    int gg = nbase + n0 + nt * 16 + lm;
    float bias = bih[gg] + bhh[gg];
    int gate = gg >> 9, j = gg & 511;
    int bid = j >> 3, np = gate * 8 + (j & 7);
    for (int mt = 0; mt < 2; ++mt)
      for (int r = 0; r < 4; ++r) {
        int m = mbase + m0 + mt * 16 + q * 4 + r;
        int tl = m >> 5, b = m & 31;
        xp[(((size_t)tl * NBLK + bid) * 32 + b) * 32 + np] = f2bf(acc[mt][nt][r] + bias);
      }
  }
}

// ---------------------------------------------------------------------------
// Persistent recurrent kernel. 64 blocks x 256 thr. Block bid owns j in
// [bid*8, bid*8+8) and all 4 gates for those j.
// Step protocol: poll(all flags >= t) -> batched h loads -> MFMA -> gates ->
// h/out stores -> syncthreads (vmcnt drain) -> flag[bid] = t+1.
__global__ __launch_bounds__(256, 1) void lstm_rec(const short* __restrict__ xp,
                                                   const short* __restrict__ Wpack,
                                                   const int* __restrict__ lens,
                                                   float* __restrict__ out,
                                                   short* hb0, short* hb1,
                                                   float* hf, float* cf,
                                                   unsigned* flags, int t0, int t1) {
  __shared__ float gl[32][33];    // gates [b][n']
  int tid = threadIdx.x, bid = blockIdx.x;
  int lane = tid & 63, wave = tid >> 6;
  int lm = lane & 15, q = lane >> 4;
  int m0 = (wave & 1) * 16, n0 = (wave >> 1) * 16;

  // W fragments in registers for the whole loop: wave's gate-col = n0+lm,
  // k = kk*32 + q*8 + 0..7  (16 frags x 16B = 64 VGPRs)
  bf16x8 wreg[16];
  {
    const short* wp = Wpack + (size_t)bid * (32 * C_N) + (size_t)(n0 + lm) * C_N + q * 8;
#pragma unroll
    for (int kk = 0; kk < 16; ++kk) wreg[kk] = *(const bf16x8*)(wp + kk * 32);
  }
  int b_ = tid >> 3, jp = tid & 7;
  int j = bid * JPB + jp;
  int len = lens[b_];
  int idx = b_ * H_N + j;
  float hcur = hf[idx], ccur = cf[idx];        // own-slice state in registers
  size_t aoff = (size_t)(m0 + lm) * H_N + q * 8;   // shorts

  // prefetch xp for first step
  float pxi, pxf, pxg, pxo;
  {
    const short* xr = xp + (((size_t)0 * NBLK + bid) * 32 + b_) * 32;
    pxi = bf2f(xr[jp]); pxf = bf2f(xr[8 + jp]);
    pxg = bf2f(xr[16 + jp]); pxo = bf2f(xr[24 + jp]);
  }

  for (int t = t0; t < t1; ++t) {
    // ---- wait: all 64 flags >= t (h_{t-1} visible). Per-wave: one gathered
    // load of all flags + ballot. flags start at 0 -> step 0 passes.
    {
      const unsigned* fp = flags + lane * 16;   // 64B stride: own line per block
      unsigned v;
      do {
        v = __hip_atomic_load(fp, __ATOMIC_RELAXED, __HIP_MEMORY_SCOPE_AGENT);
      } while (__ballot(v < (unsigned)t) != 0ull);
    }
    __asm__ __volatile__("" ::: "memory");      // pin h loads behind the poll

    const short* hrd = (t & 1) ? hb1 : hb0;     // h_{t-1}
    short*       hwr = (t & 1) ? hb0 : hb1;     // h_t
    // ---- phase 1: batched h loads -> registers (single fabric latency) ----
    // fragment i = shorts [aoff + i*32, +8) = ULL offsets {i*8, i*8+1}
    unsigned long long hq[32];
    const unsigned long long* ar = (const unsigned long long*)(hrd + aoff);
#pragma unroll
    for (int i = 0; i < 16; ++i) {
      hq[2 * i]     = __hip_atomic_load(ar + i * 8,     __ATOMIC_RELAXED, __HIP_MEMORY_SCOPE_AGENT);
      hq[2 * i + 1] = __hip_atomic_load(ar + i * 8 + 1, __ATOMIC_RELAXED, __HIP_MEMORY_SCOPE_AGENT);
    }
    __builtin_amdgcn_sched_barrier(0);          // all loads issue before MFMA
    // ---- phase 2: MFMA, four independent chains ----
    f32x4 ac0 = {0.f,0.f,0.f,0.f}, ac1 = {0.f,0.f,0.f,0.f};
    f32x4 ac2 = {0.f,0.f,0.f,0.f}, ac3 = {0.f,0.f,0.f,0.f};
#pragma unroll
    for (int kk = 0; kk < 16; kk += 4) {
      union { unsigned long long qv[2]; bf16x8 v; } a0, a1, a2, a3;
      a0.qv[0] = hq[2*kk];   a0.qv[1] = hq[2*kk+1];
      a1.qv[0] = hq[2*kk+2]; a1.qv[1] = hq[2*kk+3];
      a2.qv[0] = hq[2*kk+4]; a2.qv[1] = hq[2*kk+5];
      a3.qv[0] = hq[2*kk+6]; a3.qv[1] = hq[2*kk+7];
      ac0 = __builtin_amdgcn_mfma_f32_16x16x32_bf16(a0.v, wreg[kk],   ac0, 0, 0, 0);
      ac1 = __builtin_amdgcn_mfma_f32_16x16x32_bf16(a1.v, wreg[kk+1], ac1, 0, 0, 0);
      ac2 = __builtin_amdgcn_mfma_f32_16x16x32_bf16(a2.v, wreg[kk+2], ac2, 0, 0, 0);
      ac3 = __builtin_amdgcn_mfma_f32_16x16x32_bf16(a3.v, wreg[kk+3], ac3, 0, 0, 0);
    }
    // prefetch xp for t+1 (normal cached loads, L2-resident)
    float nxi = 0.f, nxf = 0.f, nxg = 0.f, nxo = 0.f;
    if (t + 1 < t1) {
      const short* xr = xp + (((size_t)(t + 1 - t0) * NBLK + bid) * 32 + b_) * 32;
      nxi = bf2f(xr[jp]); nxf = bf2f(xr[8 + jp]);
      nxg = bf2f(xr[16 + jp]); nxo = bf2f(xr[24 + jp]);
    }
#pragma unroll
    for (int r = 0; r < 4; ++r)
      gl[m0 + q * 4 + r][n0 + lm] = (ac0[r] + ac1[r]) + (ac2[r] + ac3[r]);
    __syncthreads();
    {
      float pi = gl[b_][jp]      + pxi;
      float pf = gl[b_][8 + jp]  + pxf;
      float pg = gl[b_][16 + jp] + pxg;
      float po = gl[b_][24 + jp] + pxo;
      float ig = sigmoid_f(pi);
      float fg = sigmoid_f(pf);
      float gv = tanh_f(pg);
      float og = sigmoid_f(po);
      float c_new = fg * ccur + ig * gv;
      float h_new = og * tanh_f(c_new);
      bool valid = t < len;
      if (valid) { ccur = c_new; hcur = h_new; }
      out[(size_t)t * (B_N * H_N) + idx] = valid ? h_new : 0.f;
      // h_t broadcast: shfl-pack 4 bf16 -> one 8B relaxed agent atomic store
      int hv = (int)(unsigned short)f2bf(hcur);
      int v1 = __shfl(hv, lane + 1);
      int v2 = __shfl(hv, lane + 2);
      int v3 = __shfl(hv, lane + 3);
      if ((jp & 3) == 0) {
        unsigned long long pk = (unsigned long long)(unsigned)hv
                              | ((unsigned long long)(unsigned)v1 << 16)
                              | ((unsigned long long)(unsigned)v2 << 32)
                              | ((unsigned long long)(unsigned)v3 << 48);
        __hip_atomic_store((unsigned long long*)(hwr + idx), pk,
                           __ATOMIC_RELAXED, __HIP_MEMORY_SCOPE_AGENT);
      }
    }
    pxi = nxi; pxf = nxf; pxg = nxg; pxo = nxo;
    __syncthreads();   // each wave drains vmcnt -> h/out stores visible
    if (tid == 0)      // arrival: own line, no cross-block contention
      __hip_atomic_store(flags + bid * 16, (unsigned)(t + 1),
                         __ATOMIC_RELAXED, __HIP_MEMORY_SCOPE_AGENT);
  }
  hf[idx] = hcur; cf[idx] = ccur;   // persist own slice for next chunk
  if (t1 == T_N) {
    out[(size_t)T_N * (B_N * H_N) + idx] = hcur;
    out[(size_t)T_N * (B_N * H_N) + (B_N * H_N) + idx] = ccur;
  }
}

// ---------------------------------------------------------------------------
extern "C" void kernel_launch(void* const* d_in, const int* in_sizes, int n_in,
                              void* d_out, int out_size, void* d_ws, size_t ws_size,
                              hipStream_t stream) {
  (void)in_sizes; (void)n_in; (void)out_size;
  const float* src = (const float*)d_in[0];
  const int*  lens = (const int*)d_in[1];
  const float* Wih = (const float*)d_in[2];
  const float* Whh = (const float*)d_in[3];
  const float* bih = (const float*)d_in[4];
  const float* bhh = (const float*)d_in[5];
  float* out = (float*)d_out;
  char* ws = (char*)d_ws;
  // ws layout: [0,32K) hb0 | [32K,64K) hb1 | [64K,128K) h_f32 | [128K,192K) c_f32 |
  //            [192K,196K) flags (64 x 64B) | [256K,256K+2M) Wpack | [+2M,...) xp
  short*    hb0   = (short*)(ws);
  short*    hb1   = (short*)(ws + 32768);
  float*    hf    = (float*)(ws + 65536);
  float*    cf    = (float*)(ws + 131072);
  unsigned* flags = (unsigned*)(ws + 196608);
  short*    Wpack = (short*)(ws + 262144);
  short*    xp    = (short*)(ws + 262144 + 2097152);
  const size_t fixed = 262144 + 2097152;

  (void)hipMemsetAsync(ws, 0, 196608 + 4096, stream);     // state + flags
  pack_whh<<<512, 256, 0, stream>>>(Whh, Wpack);

  int TC = 1024;                                          // chunk timesteps
  while (TC > 2 && fixed + (size_t)TC * (B_N * G_N * 2) > ws_size) TC >>= 1;
  for (int t0 = 0; t0 < T_N; t0 += TC) {
    xproj_gemm<<<(TC / 2) * 32, 256, 0, stream>>>(src, Wih, bih, bhh, xp, t0);
    lstm_rec<<<NBLK, 256, 0, stream>>>(xp, Wpack, lens, out, hb0, hb1, hf, cf, flags, t0, t0 + TC);
  }
}

// Round 7
// 3552.898 us; speedup vs baseline: 1.6864x; 1.6864x over previous
//
#include <hip/hip_runtime.h>
#include <hip/hip_bf16.h>
#include <stdint.h>

// LSTM: B=32, T=1024, C=512, H=512. out = [T,B,H] fp32 ++ hT[1,B,H] ++ cT[1,B,H].
// Phase 1: x-projection GEMM (bf16 MFMA), bias folded, stored bf16 in ws.
// Phase 2: persistent 64-block recurrent kernel, per-block flag barrier.
//   R7: K-split across waves (no duplicate h reads; gate partials summed via
//       4 LDS planes) + single inline-asm batch of 8x global_load_dwordx4
//       sc0 sc1 with ONE s_waitcnt (16B coherent loads, allocator-proof).
//       h transactions/block·step: 8192x8B (R6) -> 2048x16B.

#define B_N 32
#define T_N 1024
#define C_N 512
#define H_N 512
#define G_N 2048
#define NBLK 64
#define JPB 8   // H / NBLK

typedef __attribute__((ext_vector_type(8))) short bf16x8;
typedef __attribute__((ext_vector_type(4))) short s16x4;
typedef __attribute__((ext_vector_type(4))) float f32x4;

__device__ __forceinline__ short f2bf(float f) {
  union { float f; unsigned u; } x; x.f = f;
  unsigned r = x.u + 0x7fffu + ((x.u >> 16) & 1u);   // RNE
  return (short)(r >> 16);
}
__device__ __forceinline__ float bf2f(short s) {
  union { unsigned u; float f; } x; x.u = ((unsigned)(unsigned short)s) << 16;
  return x.f;
}
__device__ __forceinline__ float sigmoid_f(float x) {
  return 1.f / (1.f + __expf(-x));
}
__device__ __forceinline__ float tanh_f(float x) {
  return 1.f - 2.f / (__expf(2.f * x) + 1.f);
}

// ---------------------------------------------------------------------------
// Pack W_hh (fp32 [2048][512]) -> bf16, per-recurrent-block column order:
// Wpack[bid][n'][k], n' = gate*8 + (j&7), where g = gate*512 + j, bid = j>>3.
__global__ __launch_bounds__(256) void pack_whh(const float* __restrict__ Whh,
                                                short* __restrict__ Wpack) {
  int idx = blockIdx.x * 256 + threadIdx.x;   // 131072 threads
  int g  = idx >> 6;                          // 0..2047
  int kb = (idx & 63) * 8;                    // 0..504
  int gate = g >> 9, j = g & 511;
  int bid = j >> 3, np = gate * 8 + (j & 7);
  const float* sp = Whh + (size_t)g * C_N + kb;
  float4 v0 = *(const float4*)(sp);
  float4 v1 = *(const float4*)(sp + 4);
  bf16x8 o;
  o[0] = f2bf(v0.x); o[1] = f2bf(v0.y); o[2] = f2bf(v0.z); o[3] = f2bf(v0.w);
  o[4] = f2bf(v1.x); o[5] = f2bf(v1.y); o[6] = f2bf(v1.z); o[7] = f2bf(v1.w);
  *(bf16x8*)(Wpack + ((size_t)(bid * 32 + np)) * C_N + kb) = o;
}

// ---------------------------------------------------------------------------
// x-projection GEMM: xp[t][bid][b][n'] (bf16) = src[b][t0+t][:] . W_ih[g][:] + b_ih[g] + b_hh[g]
__global__ __launch_bounds__(256) void xproj_gemm(const float* __restrict__ src,
                                                  const float* __restrict__ Wih,
                                                  const float* __restrict__ bih,
                                                  const float* __restrict__ bhh,
                                                  short* __restrict__ xp, int t0) {
  __shared__ short As[64][72];
  __shared__ short Bs[64][72];
  int tid = threadIdx.x;
  int bn = blockIdx.x & 31, bm = blockIdx.x >> 5;
  int mbase = bm * 64, nbase = bn * 64;
  int lane = tid & 63, wave = tid >> 6;
  int lm = lane & 15, q = lane >> 4;
  int m0 = (wave & 1) * 32, n0 = (wave >> 1) * 32;
  f32x4 acc[2][2] = {};

  for (int kk = 0; kk < C_N; kk += 64) {
    for (int p = 0; p < 4; ++p) {
      int flat = p * 1024 + tid * 4;
      int r = flat >> 6, k = flat & 63;
      int m = mbase + r; int tl = m >> 5, b = m & 31;
      float4 va = *(const float4*)(src + ((size_t)b * T_N + (t0 + tl)) * C_N + kk + k);
      s16x4 pa; pa[0] = f2bf(va.x); pa[1] = f2bf(va.y); pa[2] = f2bf(va.z); pa[3] = f2bf(va.w);
      *(s16x4*)&As[r][k] = pa;
      int gg = nbase + r;
      float4 vb = *(const float4*)(Wih + (size_t)gg * C_N + kk + k);
      s16x4 pb; pb[0] = f2bf(vb.x); pb[1] = f2bf(vb.y); pb[2] = f2bf(vb.z); pb[3] = f2bf(vb.w);
      *(s16x4*)&Bs[r][k] = pb;
    }
    __syncthreads();
    for (int ks = 0; ks < 2; ++ks) {
      bf16x8 a0 = *(bf16x8*)&As[m0 + lm][ks * 32 + q * 8];
      bf16x8 a1 = *(bf16x8*)&As[m0 + 16 + lm][ks * 32 + q * 8];
      bf16x8 b0 = *(bf16x8*)&Bs[n0 + lm][ks * 32 + q * 8];
      bf16x8 b1 = *(bf16x8*)&Bs[n0 + 16 + lm][ks * 32 + q * 8];
      acc[0][0] = __builtin_amdgcn_mfma_f32_16x16x32_bf16(a0, b0, acc[0][0], 0, 0, 0);
      acc[0][1] = __builtin_amdgcn_mfma_f32_16x16x32_bf16(a0, b1, acc[0][1], 0, 0, 0);
      acc[1][0] = __builtin_amdgcn_mfma_f32_16x16x32_bf16(a1, b0, acc[1][0], 0, 0, 0);
      acc[1][1] = __builtin_amdgcn_mfma_f32_16x16x32_bf16(a1, b1, acc[1][1], 0, 0, 0);
    }
    __syncthreads();
  }
  for (int nt = 0; nt < 2; ++nt) {
    int gg = nbase + n0 + nt * 16 + lm;
    float bias = bih[gg] + bhh[gg];
    int gate = gg >> 9, j = gg & 511;
    int bid = j >> 3, np = gate * 8 + (j & 7);
    for (int mt = 0; mt < 2; ++mt)
      for (int r = 0; r < 4; ++r) {
        int m = mbase + m0 + mt * 16 + q * 4 + r;
        int tl = m >> 5, b = m & 31;
        xp[(((size_t)tl * NBLK + bid) * 32 + b) * 32 + np] = f2bf(acc[mt][nt][r] + bias);
      }
  }
}

// ---------------------------------------------------------------------------
// Persistent recurrent kernel. 64 blocks x 256 thr. Block bid owns j in
// [bid*8, bid*8+8) and all 4 gates for those j (32 gate-cols).
// K-split: wave w covers k in [w*128, (w+1)*128), both 16-row m-tiles and both
// 16-col n-tiles; partial gate sums combined through 4 LDS planes.
__global__ __launch_bounds__(256, 1) void lstm_rec(const short* __restrict__ xp,
                                                   const short* __restrict__ Wpack,
                                                   const int* __restrict__ lens,
                                                   float* __restrict__ out,
                                                   short* hb0, short* hb1,
                                                   float* hf, float* cf,
                                                   unsigned* flags, int t0, int t1) {
  __shared__ float gl[4][32][34];   // per-wave partial gates [w][b][n']
  int tid = threadIdx.x, bid = blockIdx.x;
  int lane = tid & 63, wave = tid >> 6;
  int lm = lane & 15, q = lane >> 4;

  // W fragments in registers: wreg[nt][kki], col = nt*16+lm, k = (wave*4+kki)*32+q*8
  bf16x8 wreg[2][4];
  {
    const short* wp = Wpack + (size_t)bid * (32 * C_N);
#pragma unroll
    for (int nt = 0; nt < 2; ++nt)
#pragma unroll
      for (int kki = 0; kki < 4; ++kki)
        wreg[nt][kki] = *(const bf16x8*)(wp + (size_t)(nt * 16 + lm) * C_N
                                            + (wave * 4 + kki) * 32 + q * 8);
  }
  int b_ = tid >> 3, jp = tid & 7;
  int j = bid * JPB + jp;
  int len = lens[b_];
  int idx = b_ * H_N + j;
  float hcur = hf[idx], ccur = cf[idx];        // own-slice state in registers
  // A-fragment bases (shorts): row = mt*16+lm, k = wave*128 + kki*32 + q*8
  size_t aoff0 = (size_t)lm * H_N + wave * 128 + q * 8;
  size_t aoff1 = aoff0 + 16 * H_N;

  // prefetch xp for first step
  float pxi, pxf, pxg, pxo;
  {
    const short* xr = xp + (((size_t)0 * NBLK + bid) * 32 + b_) * 32;
    pxi = bf2f(xr[jp]); pxf = bf2f(xr[8 + jp]);
    pxg = bf2f(xr[16 + jp]); pxo = bf2f(xr[24 + jp]);
  }

  for (int t = t0; t < t1; ++t) {
    // ---- wait: all 64 flags >= t (h_{t-1} visible across XCDs) ----
    {
      const unsigned* fp = flags + lane * 16;   // 64B stride: own line per block
      unsigned v;
      do {
        v = __hip_atomic_load(fp, __ATOMIC_RELAXED, __HIP_MEMORY_SCOPE_AGENT);
      } while (__ballot(v < (unsigned)t) != 0ull);
    }
    const short* hrd = (t & 1) ? hb1 : hb0;     // h_{t-1}
    short*       hwr = (t & 1) ? hb0 : hb1;     // h_t

    // ---- phase 1: 8x 16B coherent loads, one batch, one waitcnt ----
    bf16x8 a0[4], a1[4];
    {
      const short* p0 = hrd + aoff0;
      const short* p1 = hrd + aoff1;
      asm volatile(
        "global_load_dwordx4 %0, %[p0], off sc0 sc1\n\t"
        "global_load_dwordx4 %1, %[p0], off offset:64 sc0 sc1\n\t"
        "global_load_dwordx4 %2, %[p0], off offset:128 sc0 sc1\n\t"
        "global_load_dwordx4 %3, %[p0], off offset:192 sc0 sc1\n\t"
        "global_load_dwordx4 %4, %[p1], off sc0 sc1\n\t"
        "global_load_dwordx4 %5, %[p1], off offset:64 sc0 sc1\n\t"
        "global_load_dwordx4 %6, %[p1], off offset:128 sc0 sc1\n\t"
        "global_load_dwordx4 %7, %[p1], off offset:192 sc0 sc1\n\t"
        "s_waitcnt vmcnt(0)"
        : "=&v"(a0[0]), "=&v"(a0[1]), "=&v"(a0[2]), "=&v"(a0[3]),
          "=&v"(a1[0]), "=&v"(a1[1]), "=&v"(a1[2]), "=&v"(a1[3])
        : [p0]"v"(p0), [p1]"v"(p1)
        : "memory");
    }
    // ---- phase 2: MFMA, 4 independent chains of depth 4 ----
    f32x4 acc[2][2] = {};
#pragma unroll
    for (int kki = 0; kki < 4; ++kki) {
      acc[0][0] = __builtin_amdgcn_mfma_f32_16x16x32_bf16(a0[kki], wreg[0][kki], acc[0][0], 0, 0, 0);
      acc[0][1] = __builtin_amdgcn_mfma_f32_16x16x32_bf16(a0[kki], wreg[1][kki], acc[0][1], 0, 0, 0);
      acc[1][0] = __builtin_amdgcn_mfma_f32_16x16x32_bf16(a1[kki], wreg[0][kki], acc[1][0], 0, 0, 0);
      acc[1][1] = __builtin_amdgcn_mfma_f32_16x16x32_bf16(a1[kki], wreg[1][kki], acc[1][1], 0, 0, 0);
    }
    // prefetch xp for t+1 (normal cached loads, L2-resident)
    float nxi = 0.f, nxf = 0.f, nxg = 0.f, nxo = 0.f;
    if (t + 1 < t1) {
      const short* xr = xp + (((size_t)(t + 1 - t0) * NBLK + bid) * 32 + b_) * 32;
      nxi = bf2f(xr[jp]); nxf = bf2f(xr[8 + jp]);
      nxg = bf2f(xr[16 + jp]); nxo = bf2f(xr[24 + jp]);
    }
#pragma unroll
    for (int mt = 0; mt < 2; ++mt)
#pragma unroll
      for (int nt = 0; nt < 2; ++nt)
#pragma unroll
        for (int r = 0; r < 4; ++r)
          gl[wave][mt * 16 + q * 4 + r][nt * 16 + lm] = acc[mt][nt][r];
    __syncthreads();
    {
      float pi = gl[0][b_][jp]      + gl[1][b_][jp]      + gl[2][b_][jp]      + gl[3][b_][jp]      + pxi;
      float pf = gl[0][b_][8 + jp]  + gl[1][b_][8 + jp]  + gl[2][b_][8 + jp]  + gl[3][b_][8 + jp]  + pxf;
      float pg = gl[0][b_][16 + jp] + gl[1][b_][16 + jp] + gl[2][b_][16 + jp] + gl[3][b_][16 + jp] + pxg;
      float po = gl[0][b_][24 + jp] + gl[1][b_][24 + jp] + gl[2][b_][24 + jp] + gl[3][b_][24 + jp] + pxo;
      float ig = sigmoid_f(pi);
      float fg = sigmoid_f(pf);
      float gv = tanh_f(pg);
      float og = sigmoid_f(po);
      float c_new = fg * ccur + ig * gv;
      float h_new = og * tanh_f(c_new);
      bool valid = t < len;
      if (valid) { ccur = c_new; hcur = h_new; }
      out[(size_t)t * (B_N * H_N) + idx] = valid ? h_new : 0.f;
      // h_t broadcast: shfl-pack 4 bf16 -> one 8B relaxed agent atomic store
      int hv = (int)(unsigned short)f2bf(hcur);
      int v1 = __shfl(hv, lane + 1);
      int v2 = __shfl(hv, lane + 2);
      int v3 = __shfl(hv, lane + 3);
      if ((jp & 3) == 0) {
        unsigned long long pk = (unsigned long long)(unsigned)hv
                              | ((unsigned long long)(unsigned)v1 << 16)
                              | ((unsigned long long)(unsigned)v2 << 32)
                              | ((unsigned long long)(unsigned)v3 << 48);
        __hip_atomic_store((unsigned long long*)(hwr + idx), pk,
                           __ATOMIC_RELAXED, __HIP_MEMORY_SCOPE_AGENT);
      }
    }
    pxi = nxi; pxf = nxf; pxg = nxg; pxo = nxo;
    __syncthreads();   // each wave drains vmcnt -> h/out stores visible
    if (tid == 0)      // arrival: own 64B line, no cross-block contention
      __hip_atomic_store(flags + bid * 16, (unsigned)(t + 1),
                         __ATOMIC_RELAXED, __HIP_MEMORY_SCOPE_AGENT);
  }
  hf[idx] = hcur; cf[idx] = ccur;   // persist own slice for next chunk
  if (t1 == T_N) {
    out[(size_t)T_N * (B_N * H_N) + idx] = hcur;
    out[(size_t)T_N * (B_N * H_N) + (B_N * H_N) + idx] = ccur;
  }
}

// ---------------------------------------------------------------------------
extern "C" void kernel_launch(void* const* d_in, const int* in_sizes, int n_in,
                              void* d_out, int out_size, void* d_ws, size_t ws_size,
                              hipStream_t stream) {
  (void)in_sizes; (void)n_in; (void)out_size;
  const float* src = (const float*)d_in[0];
  const int*  lens = (const int*)d_in[1];
  const float* Wih = (const float*)d_in[2];
  const float* Whh = (const float*)d_in[3];
  const float* bih = (const float*)d_in[4];
  const float* bhh = (const float*)d_in[5];
  float* out = (float*)d_out;
  char* ws = (char*)d_ws;
  // ws layout: [0,32K) hb0 | [32K,64K) hb1 | [64K,128K) h_f32 | [128K,192K) c_f32 |
  //            [192K,196K) flags (64 x 64B) | [256K,256K+2M) Wpack | [+2M,...) xp
  short*    hb0   = (short*)(ws);
  short*    hb1   = (short*)(ws + 32768);
  float*    hf    = (float*)(ws + 65536);
  float*    cf    = (float*)(ws + 131072);
  unsigned* flags = (unsigned*)(ws + 196608);
  short*    Wpack = (short*)(ws + 262144);
  short*    xp    = (short*)(ws + 262144 + 2097152);
  const size_t fixed = 262144 + 2097152;

  (void)hipMemsetAsync(ws, 0, 196608 + 4096, stream);     // state + flags
  pack_whh<<<512, 256, 0, stream>>>(Whh, Wpack);

  int TC = 1024;                                          // chunk timesteps
  while (TC > 2 && fixed + (size_t)TC * (B_N * G_N * 2) > ws_size) TC >>= 1;
  for (int t0 = 0; t0 < T_N; t0 += TC) {
    xproj_gemm<<<(TC / 2) * 32, 256, 0, stream>>>(src, Wih, bih, bhh, xp, t0);
    lstm_rec<<<NBLK, 256, 0, stream>>>(xp, Wpack, lens, out, hb0, hb1, hf, cf, flags, t0, t0 + TC);
  }
}